// Round 20
// baseline (98.211 us; speedup 1.0000x reference)
//
#include <hip/hip_runtime.h>

typedef short short4v __attribute__((ext_vector_type(4)));
typedef short short8 __attribute__((ext_vector_type(8)));
typedef float floatx4 __attribute__((ext_vector_type(4)));

// Native bf16 conversion: compiler emits packed v_cvt_pk_bf16_f32 (RTNE).
__device__ __forceinline__ short f2bf(float f) {
    __bf16 h = (__bf16)f;
    return __builtin_bit_cast(short, h);
}

// Convert lora_A (4096x64) and lora_B (64x4096) fp32 -> bf16 in MFMA fragment
// layout for mfma_f32_16x16x32_bf16:
//   lane l holds elem[k][c] with c = l&15, k = 8*(l>>4) + j, j=0..7
__global__ __launch_bounds__(256) void conv_ab(
    const float* __restrict__ A, const float* __restrict__ B,
    short* __restrict__ Abf, short* __restrict__ Bbf) {
    int i = blockIdx.x * 256 + threadIdx.x;   // 0 .. 262143
    int j    = i & 7;
    int lane = (i >> 3) & 63;
    int hi   = i >> 9;                        // A: ks*4+nt ; B: ct*2+ks
    int krow = 8 * (lane >> 4) + j;
    int cc   = lane & 15;
    {   // A fragments
        int ks = hi >> 2, nt = hi & 3;
        Abf[i] = f2bf(A[(size_t)(ks * 32 + krow) * 64 + nt * 16 + cc]);
    }
    {   // B fragments
        int ct = hi >> 1, ks = hi & 1;
        Bbf[i] = f2bf(B[(size_t)(ks * 32 + krow) * 4096 + ct * 16 + cc]);
    }
}

// Fused: block = 16 rows. Phase 1 = operand-swapped x@A (2-deep rotating
// pipeline; wave w owns K-slice 1024) -> f32 partials in LDS. Reduce -> bf16
// t in LDS. Phase 2 = per 256-col strip x16: 8 MFMA -> LDS tile -> row-linear
// 256B NT stores. `tile` unions over dead `red`.
// R19 lever: __launch_bounds__(256, 6) -> 6 blocks/CU co-resident (LDS 113KB,
// VGPR cap 85 >= ~48 used): +50% resident waves AND +50% phase-skew diversity
// (more blocks on a CU in different read/write phases).
__global__ __launch_bounds__(256, 6) void fused(
    const float* __restrict__ x, const float* __restrict__ tw,
    const short* __restrict__ Abf, const short* __restrict__ Bbf,
    float* __restrict__ out) {
    __shared__ union {
        float red[4][16][65];             // phase-1 per-wave partials (16.6 KB)
        float tile[16][257];              // phase-2 store staging (16.4 KB)
    } sh;
    __shared__ short tl[16][72];          // reduced t, bf16; 144B rows (16B-mult)

    const int lane = threadIdx.x & 63;
    const int wave = threadIdx.x >> 6;    // 0..3
    const int rowbase = blockIdx.x * 16;
    const int rrow = lane & 15;
    const int kgrp = lane >> 4;           // 0..3
    const int row = rowbase + rrow;

    // ---------------- phase 1: t-partial = x @ A over K-slice 1024 ----------------
    {
        const int kbase = wave * 1024;
        const bool active = (tw[row] != 0.0f);
        const floatx4* xv = (const floatx4*)(x + (size_t)row * 4096 + kbase + kgrp * 8);
        // Abf8[(ksg*4+nt)*64 + lane], ksg = kbase/32 + ks
        const short8* ap = (const short8*)Abf + ((size_t)(kbase >> 5) * 256) + lane;

        floatx4 acc0 = {0,0,0,0}, acc1 = {0,0,0,0}, acc2 = {0,0,0,0}, acc3 = {0,0,0,0};

        floatx4 px[2][2];
        short8  pb[2][4];
        #pragma unroll
        for (int s = 0; s < 2; ++s) {
            px[s][0] = (floatx4){0,0,0,0};
            px[s][1] = (floatx4){0,0,0,0};
            if (active) { px[s][0] = xv[s * 8]; px[s][1] = xv[s * 8 + 1]; }
            pb[s][0] = ap[s * 256 + 0 * 64];
            pb[s][1] = ap[s * 256 + 1 * 64];
            pb[s][2] = ap[s * 256 + 2 * 64];
            pb[s][3] = ap[s * 256 + 3 * 64];
        }

        #pragma unroll
        for (int ks = 0; ks < 32; ++ks) {
            const int s = ks & 1;
            short8 xa;
            xa[0] = f2bf(px[s][0][0]); xa[1] = f2bf(px[s][0][1]);
            xa[2] = f2bf(px[s][0][2]); xa[3] = f2bf(px[s][0][3]);
            xa[4] = f2bf(px[s][1][0]); xa[5] = f2bf(px[s][1][1]);
            xa[6] = f2bf(px[s][1][2]); xa[7] = f2bf(px[s][1][3]);
            short8 b0 = pb[s][0], b1 = pb[s][1], b2 = pb[s][2], b3 = pb[s][3];

            if (ks + 2 < 32) {
                if (active) { px[s][0] = xv[(ks + 2) * 8]; px[s][1] = xv[(ks + 2) * 8 + 1]; }
                pb[s][0] = ap[(size_t)(ks + 2) * 256 + 0 * 64];
                pb[s][1] = ap[(size_t)(ks + 2) * 256 + 1 * 64];
                pb[s][2] = ap[(size_t)(ks + 2) * 256 + 2 * 64];
                pb[s][3] = ap[(size_t)(ks + 2) * 256 + 3 * 64];
            }

            // swapped: A-matrix fragment as A-operand, x fragment as B-operand.
            // D[m][n] = sum_k A[kbase+k][nt*16+m] * x[rowbase+n][kbase+k]
            acc0 = __builtin_amdgcn_mfma_f32_16x16x32_bf16(b0, xa, acc0, 0, 0, 0);
            acc1 = __builtin_amdgcn_mfma_f32_16x16x32_bf16(b1, xa, acc1, 0, 0, 0);
            acc2 = __builtin_amdgcn_mfma_f32_16x16x32_bf16(b2, xa, acc2, 0, 0, 0);
            acc3 = __builtin_amdgcn_mfma_f32_16x16x32_bf16(b3, xa, acc3, 0, 0, 0);
        }

        // D layout: lane holds t_p[row][nt*16 + kgrp*4 + 0..3] -> float4 to LDS
        floatx4 accs[4] = {acc0, acc1, acc2, acc3};
        #pragma unroll
        for (int nt = 0; nt < 4; ++nt)
            *(floatx4*)&sh.red[wave][rrow][nt * 16 + kgrp * 4] = accs[nt];
    }
    __syncthreads();

    // ---------------- reduce 4 partials -> bf16 t in LDS ----------------
    {
        const int r = threadIdx.x >> 4;
        const int c = (threadIdx.x & 15) * 4;
        floatx4 v0 = *(const floatx4*)&sh.red[0][r][c];
        floatx4 v1 = *(const floatx4*)&sh.red[1][r][c];
        floatx4 v2 = *(const floatx4*)&sh.red[2][r][c];
        floatx4 v3 = *(const floatx4*)&sh.red[3][r][c];
        floatx4 sum = v0 + v1 + v2 + v3;
        short4v r4;
        r4[0] = f2bf(sum[0]); r4[1] = f2bf(sum[1]);
        r4[2] = f2bf(sum[2]); r4[3] = f2bf(sum[3]);
        *(short4v*)&tl[r][c] = r4;
    }
    __syncthreads();

    // ---------------- phase 2: out = (t @ B) * tw * 2, 16 strips of 256 cols ----------------
    // t fragment (MFMA B-operand after swap): lane holds t[rrow][kgrp*8 + j]
    short8 a0 = *(const short8*)&tl[rrow][kgrp * 8];
    short8 a1 = *(const short8*)&tl[rrow][32 + kgrp * 8];
    const float w = tw[row] * 2.0f;
    const int orow_i = 4 * wave + kgrp;
    float* orow = out + (size_t)(rowbase + orow_i) * 4096;

    #pragma unroll 2
    for (int s = 0; s < 16; ++s) {
        const int colblk = s * 256;
        // B fragments (MFMA A-operand): Bbf8[(ct*2+ks)*64 + lane], ct = col/16
        const short8* bp = (const short8*)Bbf
                         + (size_t)((colblk + wave * 64) >> 4) * 128 + lane;
        #pragma unroll
        for (int nt = 0; nt < 4; ++nt) {
            short8 b0 = bp[(nt * 2 + 0) * 64];
            short8 b1 = bp[(nt * 2 + 1) * 64];
            floatx4 acc = {0, 0, 0, 0};
            // swapped: lane holds out[rrow][wave*64 + nt*16 + kgrp*4 + 0..3]
            acc = __builtin_amdgcn_mfma_f32_16x16x32_bf16(b0, a0, acc, 0, 0, 0);
            acc = __builtin_amdgcn_mfma_f32_16x16x32_bf16(b1, a1, acc, 0, 0, 0);
            acc[0] *= w; acc[1] *= w; acc[2] *= w; acc[3] *= w;
            *(floatx4*)&sh.tile[rrow][wave * 64 + nt * 16 + kgrp * 4] = acc;
        }
        __syncthreads();
        // row-linear write-out: lane -> row 4*wave+kgrp, 16B chunk rrow*16B
        // within each 64-float column group q: 16 lanes cover 256B contiguous.
        #pragma unroll
        for (int q = 0; q < 4; ++q) {
            const int c = q * 64 + rrow * 4;
            floatx4 v = *(const floatx4*)&sh.tile[orow_i][c];
            __builtin_nontemporal_store(v, (floatx4*)(orow + colblk + c));
        }
        __syncthreads();   // protect tile before next strip overwrites it
    }
}

extern "C" void kernel_launch(void* const* d_in, const int* in_sizes, int n_in,
                              void* d_out, int out_size, void* d_ws, size_t ws_size,
                              hipStream_t stream) {
    const float* x  = (const float*)d_in[0];   // (8,2048,4096)
    const float* tw = (const float*)d_in[1];   // (8,2048)
    const float* A  = (const float*)d_in[2];   // (4096,64)
    const float* B  = (const float*)d_in[3];   // (64,4096)
    float* out = (float*)d_out;                // (8,2048,4096) fp32

    short* Abf = (short*)d_ws;                 // 512 KB
    short* Bbf = Abf + 262144;                 // 512 KB

    conv_ab<<<1024, 256, 0, stream>>>(A, B, Abf, Bbf);
    fused<<<1024, 256, 0, stream>>>(x, tw, Abf, Bbf, out);
}

// Round 21
// 80.334 us; speedup vs baseline: 1.2225x; 1.2225x over previous
//
#include <hip/hip_runtime.h>

typedef short short4v __attribute__((ext_vector_type(4)));
typedef short short8 __attribute__((ext_vector_type(8)));
typedef float floatx4 __attribute__((ext_vector_type(4)));

// Native bf16 conversion: compiler emits packed v_cvt_pk_bf16_f32 (RTNE).
__device__ __forceinline__ short f2bf(float f) {
    __bf16 h = (__bf16)f;
    return __builtin_bit_cast(short, h);
}

// Convert lora_A (4096x64) and lora_B (64x4096) fp32 -> bf16 in MFMA fragment
// layout for mfma_f32_16x16x32_bf16:
//   lane l holds elem[k][c] with c = l&15, k = 8*(l>>4) + j, j=0..7
__global__ __launch_bounds__(256) void conv_ab(
    const float* __restrict__ A, const float* __restrict__ B,
    short* __restrict__ Abf, short* __restrict__ Bbf) {
    int i = blockIdx.x * 256 + threadIdx.x;   // 0 .. 262143
    int j    = i & 7;
    int lane = (i >> 3) & 63;
    int hi   = i >> 9;                        // A: ks*4+nt ; B: ct*2+ks
    int krow = 8 * (lane >> 4) + j;
    int cc   = lane & 15;
    {   // A fragments
        int ks = hi >> 2, nt = hi & 3;
        Abf[i] = f2bf(A[(size_t)(ks * 32 + krow) * 64 + nt * 16 + cc]);
    }
    {   // B fragments
        int ct = hi >> 1, ks = hi & 1;
        Bbf[i] = f2bf(B[(size_t)(ks * 32 + krow) * 4096 + ct * 16 + cc]);
    }
}

// Fused (R19 winning config: __launch_bounds__(256,4)): block = 16 rows.
// Phase 1 = operand-swapped x@A (2-deep rotating pipeline; wave w owns
// K-slice 1024) -> f32 partials in LDS. Reduce -> bf16 t in LDS.
// Phase 2 = per 256-col strip x16: 8 MFMA -> DOUBLE-BUFFERED LDS tile ->
// one barrier -> row-linear 256B NT stores, NO trailing barrier: strip s+1
// overwrites the other buffer, so the NT-store drain (vmcnt(0) at the next
// barrier) overlaps a full strip of MFMA+LDS work instead of serializing
// (R20 lever: the trailing barrier forced a store drain 16x/block).
__global__ __launch_bounds__(256, 4) void fused(
    const float* __restrict__ x, const float* __restrict__ tw,
    const short* __restrict__ Abf, const short* __restrict__ Bbf,
    float* __restrict__ out) {
    __shared__ union {
        float red[4][16][65];             // phase-1 per-wave partials (16.6 KB)
        float tile[2][16][257];           // phase-2 double-buffered staging (32.9 KB)
    } sh;
    __shared__ short tl[16][72];          // reduced t, bf16; 144B rows (16B-mult)

    const int lane = threadIdx.x & 63;
    const int wave = threadIdx.x >> 6;    // 0..3
    const int rowbase = blockIdx.x * 16;
    const int rrow = lane & 15;
    const int kgrp = lane >> 4;           // 0..3
    const int row = rowbase + rrow;

    // ---------------- phase 1: t-partial = x @ A over K-slice 1024 ----------------
    {
        const int kbase = wave * 1024;
        const bool active = (tw[row] != 0.0f);
        const floatx4* xv = (const floatx4*)(x + (size_t)row * 4096 + kbase + kgrp * 8);
        // Abf8[(ksg*4+nt)*64 + lane], ksg = kbase/32 + ks
        const short8* ap = (const short8*)Abf + ((size_t)(kbase >> 5) * 256) + lane;

        floatx4 acc0 = {0,0,0,0}, acc1 = {0,0,0,0}, acc2 = {0,0,0,0}, acc3 = {0,0,0,0};

        floatx4 px[2][2];
        short8  pb[2][4];
        #pragma unroll
        for (int s = 0; s < 2; ++s) {
            px[s][0] = (floatx4){0,0,0,0};
            px[s][1] = (floatx4){0,0,0,0};
            if (active) { px[s][0] = xv[s * 8]; px[s][1] = xv[s * 8 + 1]; }
            pb[s][0] = ap[s * 256 + 0 * 64];
            pb[s][1] = ap[s * 256 + 1 * 64];
            pb[s][2] = ap[s * 256 + 2 * 64];
            pb[s][3] = ap[s * 256 + 3 * 64];
        }

        #pragma unroll
        for (int ks = 0; ks < 32; ++ks) {
            const int s = ks & 1;
            short8 xa;
            xa[0] = f2bf(px[s][0][0]); xa[1] = f2bf(px[s][0][1]);
            xa[2] = f2bf(px[s][0][2]); xa[3] = f2bf(px[s][0][3]);
            xa[4] = f2bf(px[s][1][0]); xa[5] = f2bf(px[s][1][1]);
            xa[6] = f2bf(px[s][1][2]); xa[7] = f2bf(px[s][1][3]);
            short8 b0 = pb[s][0], b1 = pb[s][1], b2 = pb[s][2], b3 = pb[s][3];

            if (ks + 2 < 32) {
                if (active) { px[s][0] = xv[(ks + 2) * 8]; px[s][1] = xv[(ks + 2) * 8 + 1]; }
                pb[s][0] = ap[(size_t)(ks + 2) * 256 + 0 * 64];
                pb[s][1] = ap[(size_t)(ks + 2) * 256 + 1 * 64];
                pb[s][2] = ap[(size_t)(ks + 2) * 256 + 2 * 64];
                pb[s][3] = ap[(size_t)(ks + 2) * 256 + 3 * 64];
            }

            // swapped: A-matrix fragment as A-operand, x fragment as B-operand.
            // D[m][n] = sum_k A[kbase+k][nt*16+m] * x[rowbase+n][kbase+k]
            acc0 = __builtin_amdgcn_mfma_f32_16x16x32_bf16(b0, xa, acc0, 0, 0, 0);
            acc1 = __builtin_amdgcn_mfma_f32_16x16x32_bf16(b1, xa, acc1, 0, 0, 0);
            acc2 = __builtin_amdgcn_mfma_f32_16x16x32_bf16(b2, xa, acc2, 0, 0, 0);
            acc3 = __builtin_amdgcn_mfma_f32_16x16x32_bf16(b3, xa, acc3, 0, 0, 0);
        }

        // D layout: lane holds t_p[row][nt*16 + kgrp*4 + 0..3] -> float4 to LDS
        floatx4 accs[4] = {acc0, acc1, acc2, acc3};
        #pragma unroll
        for (int nt = 0; nt < 4; ++nt)
            *(floatx4*)&sh.red[wave][rrow][nt * 16 + kgrp * 4] = accs[nt];
    }
    __syncthreads();

    // ---------------- reduce 4 partials -> bf16 t in LDS ----------------
    {
        const int r = threadIdx.x >> 4;
        const int c = (threadIdx.x & 15) * 4;
        floatx4 v0 = *(const floatx4*)&sh.red[0][r][c];
        floatx4 v1 = *(const floatx4*)&sh.red[1][r][c];
        floatx4 v2 = *(const floatx4*)&sh.red[2][r][c];
        floatx4 v3 = *(const floatx4*)&sh.red[3][r][c];
        floatx4 sum = v0 + v1 + v2 + v3;
        short4v r4;
        r4[0] = f2bf(sum[0]); r4[1] = f2bf(sum[1]);
        r4[2] = f2bf(sum[2]); r4[3] = f2bf(sum[3]);
        *(short4v*)&tl[r][c] = r4;
    }
    __syncthreads();   // red dead after this point; tile may overwrite it

    // ---------------- phase 2: out = (t @ B) * tw * 2, 16 strips of 256 cols ----------------
    // t fragment (MFMA B-operand after swap): lane holds t[rrow][kgrp*8 + j]
    short8 a0 = *(const short8*)&tl[rrow][kgrp * 8];
    short8 a1 = *(const short8*)&tl[rrow][32 + kgrp * 8];
    const float w = tw[row] * 2.0f;
    const int orow_i = 4 * wave + kgrp;
    float* orow = out + (size_t)(rowbase + orow_i) * 4096;

    #pragma unroll 2
    for (int s = 0; s < 16; ++s) {
        const int colblk = s * 256;
        const int buf = s & 1;
        // B fragments (MFMA A-operand): Bbf8[(ct*2+ks)*64 + lane], ct = col/16
        const short8* bp = (const short8*)Bbf
                         + (size_t)((colblk + wave * 64) >> 4) * 128 + lane;
        #pragma unroll
        for (int nt = 0; nt < 4; ++nt) {
            short8 b0 = bp[(nt * 2 + 0) * 64];
            short8 b1 = bp[(nt * 2 + 1) * 64];
            floatx4 acc = {0, 0, 0, 0};
            // swapped: lane holds out[rrow][wave*64 + nt*16 + kgrp*4 + 0..3]
            acc = __builtin_amdgcn_mfma_f32_16x16x32_bf16(b0, a0, acc, 0, 0, 0);
            acc = __builtin_amdgcn_mfma_f32_16x16x32_bf16(b1, a1, acc, 0, 0, 0);
            acc[0] *= w; acc[1] *= w; acc[2] *= w; acc[3] *= w;
            *(floatx4*)&sh.tile[buf][rrow][wave * 64 + nt * 16 + kgrp * 4] = acc;
        }
        __syncthreads();   // all waves wrote tile[buf]; also drains PREVIOUS
                           // strip's NT stores (one strip of work later).
        // row-linear write-out: lane -> row 4*wave+kgrp, 16B chunk rrow*16B
        // within each 64-float column group q: 16 lanes cover 256B contiguous.
        #pragma unroll
        for (int q = 0; q < 4; ++q) {
            const int c = q * 64 + rrow * 4;
            floatx4 v = *(const floatx4*)&sh.tile[buf][orow_i][c];
            __builtin_nontemporal_store(v, (floatx4*)(orow + colblk + c));
        }
        // no trailing barrier: next strip writes tile[buf^1], whose readers
        // all finished before THIS strip's barrier.
    }
}

extern "C" void kernel_launch(void* const* d_in, const int* in_sizes, int n_in,
                              void* d_out, int out_size, void* d_ws, size_t ws_size,
                              hipStream_t stream) {
    const float* x  = (const float*)d_in[0];   // (8,2048,4096)
    const float* tw = (const float*)d_in[1];   // (8,2048)
    const float* A  = (const float*)d_in[2];   // (4096,64)
    const float* B  = (const float*)d_in[3];   // (64,4096)
    float* out = (float*)d_out;                // (8,2048,4096) fp32

    short* Abf = (short*)d_ws;                 // 512 KB
    short* Bbf = Abf + 262144;                 // 512 KB

    conv_ab<<<1024, 256, 0, stream>>>(A, B, Abf, Bbf);
    fused<<<1024, 256, 0, stream>>>(x, tw, Abf, Bbf, out);
}